// Round 10
// baseline (545.657 us; speedup 1.0000x reference)
//
#include <hip/hip_runtime.h>
#include <cstdint>

#define E_  8
#define H_  1024
#define I_  2048
#define T_  4096
#define D2_ 4096      // 2*I
#define K2_ 16384     // E*I

typedef __bf16 bf16x8 __attribute__((ext_vector_type(8)));
typedef float  f32x4  __attribute__((ext_vector_type(4)));

__device__ __forceinline__ unsigned short f2bf(float f) {
  unsigned int u = __float_as_uint(f);
  u += 0x7FFFu + ((u >> 16) & 1u);           // round-to-nearest-even
  return (unsigned short)(u >> 16);
}

// async global->LDS, 16B per lane. LDS dest must be wave-uniform base + lane*16.
__device__ __forceinline__ void gll16(const void* g, void* l) {
  __builtin_amdgcn_global_load_lds(
      (const __attribute__((address_space(1))) unsigned int*)(uintptr_t)g,
      (__attribute__((address_space(3))) unsigned int*)(uintptr_t)l,
      16, 0, 0);
}

#define BARX()  __builtin_amdgcn_s_barrier()
#define FENCE() __builtin_amdgcn_sched_barrier(0)
#define LGK0()  asm volatile("s_waitcnt lgkmcnt(0)" ::: "memory")
#define WVM0()  asm volatile("s_waitcnt vmcnt(0)" ::: "memory")

// ---------------- kernel 1: cast hidden_states fp32 -> bf16 ----------------
__global__ void cast_x_kernel(const float* __restrict__ x,
                              unsigned short* __restrict__ xb) {
  const int idx = (blockIdx.x * 256 + threadIdx.x) * 8;
  float4 a = *(const float4*)(x + idx);
  float4 b = *(const float4*)(x + idx + 4);
  unsigned short o[8];
  o[0]=f2bf(a.x); o[1]=f2bf(a.y); o[2]=f2bf(a.z); o[3]=f2bf(a.w);
  o[4]=f2bf(b.x); o[5]=f2bf(b.y); o[6]=f2bf(b.z); o[7]=f2bf(b.w);
  *(uint4*)(xb + idx) = *(const uint4*)o;
}

// ============================================================================
// Packed B layout (both GEMMs): fragment tiles of 16 rows x 32 k.
//   flat = ((rb * (K/32) + kb) * 512) + arow*32 + q*8 + e8
// where rb=r>>4, arow=r&15, kb=k>>5, q=(k>>3)&3, e8=k&7.
// A wave's B-fragment (16 rows x 32 k) is then ONE coalesced 1 KiB segment:
// lane(arow,q) reads elems arow*32+q*8 .. +8 (intra-segment permutation).
// ============================================================================

// ---- kernel 2: gate_up_proj (E,H,2I) fp32 -> packed W1g/W1u bf16 -----------
__global__ void transp_w1_kernel(const float* __restrict__ gup,
                                 unsigned short* __restrict__ w1g,
                                 unsigned short* __restrict__ w1u) {
  __shared__ float tile[64][65];
  const int h0 = blockIdx.x * 64;
  const int d0 = blockIdx.y * 64;
  const int e  = blockIdx.z;
  const int tid = threadIdx.x;
  const int r  = tid >> 4;
  const int c4 = (tid & 15) * 4;
  const float* src = gup + ((size_t)e * H_ + h0) * D2_ + d0;
#pragma unroll
  for (int c = 0; c < 4; ++c) {
    const int row = r + 16 * c;
    float4 v = *(const float4*)(src + (size_t)row * D2_ + c4);
    tile[row][c4+0] = v.x; tile[row][c4+1] = v.y;
    tile[row][c4+2] = v.z; tile[row][c4+3] = v.w;
  }
  __syncthreads();
  const int hl = tid & 63;
  const int jg = tid >> 6;
  const int h  = h0 + hl;
  // h-dependent part of packed index (K = H here, K/32 = 32)
  const size_t hterm = (size_t)(h >> 5) * 512 + ((h >> 3) & 3) * 8 + (h & 7);
#pragma unroll
  for (int jj = 0; jj < 8; ++jj) {
    const int jl = jg * 8 + jj;
    const int jE = (d0 >> 1) + jl;                    // j within expert
    const size_t gidx = (size_t)(e * 128 + (jE >> 4)) * 16384   // jb*32*512
                      + hterm + (jE & 15) * 32;
    w1g[gidx] = f2bf(tile[hl][2*jl]);
    w1u[gidx] = f2bf(tile[hl][2*jl+1]);
  }
}

// ---- kernel 3: down_proj (E,I,H) fp32 -> packed W2T bf16 -------------------
// rows = h (H total), K = E*I = 16384 (K/32 = 512 kb tiles per row-block)
__global__ void transp_w2_kernel(const float* __restrict__ dp,
                                 unsigned short* __restrict__ w2t) {
  __shared__ float tile[64][65];
  const int k0 = blockIdx.x * 64;
  const int h0 = blockIdx.y * 64;
  const int tid = threadIdx.x;
  const int r  = tid >> 4;
  const int c4 = (tid & 15) * 4;
#pragma unroll
  for (int c = 0; c < 4; ++c) {
    const int row = r + 16 * c;
    float4 v = *(const float4*)(dp + (size_t)(k0 + row) * H_ + h0 + c4);
    tile[row][c4+0] = v.x; tile[row][c4+1] = v.y;
    tile[row][c4+2] = v.z; tile[row][c4+3] = v.w;
  }
  __syncthreads();
  const int kl = tid & 63;
  const int hg = tid >> 6;
  const int k  = k0 + kl;
  const size_t kterm = (size_t)(k >> 5) * 512 + ((k >> 3) & 3) * 8 + (k & 7);
#pragma unroll
  for (int hh = 0; hh < 16; ++hh) {
    const int hl = hg * 16 + hh;
    const int h  = h0 + hl;
    const size_t gidx = (size_t)(h >> 4) * 262144      // hb*512*512
                      + kterm + (h & 15) * 32;
    w2t[gidx] = f2bf(tile[kl][hl]);
  }
}

// ============================================================================
// GEMM1: 256x128 tile, BK=64. A staged in LDS (64 KiB dbuf, XOR-swizzled,
// gll16). B (w1g/w1u, packed) streamed global->registers: 8 coalesced 1KiB
// fragment loads per wave per K-tile. One barrier + one lgkm drain + one
// vmcnt drain per K-tile (R5-proven ledger).
// LDS per buf (shorts): A[256*64]. Swizzle: phys granule = logical ^ (row&7).
// ============================================================================

#define NT1 16

#define STA1(B, HF, KT) {                                                     \
  _Pragma("unroll")                                                           \
  for (int ld = 0; ld < 2; ++ld) {                                            \
    const int r = rA + (HF)*64 + ld*128;                                      \
    gll16(Ag + (size_t)r * H_ + (KT)*64 + sg, &lds[B][r*64 + sl]);            \
  } }
#define LDA1(B, MH) {                                                         \
  _Pragma("unroll")                                                           \
  for (int m = 0; m < 4; ++m) {                                               \
    const int ro = (wm*128 + (MH)*64 + m*16 + arow) * 64;                     \
    av[m][0] = *(const bf16x8*)&lds[B][ro + sw0];                             \
    av[m][1] = *(const bf16x8*)&lds[B][ro + sw1];                             \
  } }
// B fragments from packed global: tile offset (KT*2+kk)*512 elems
#define LDBG1(KT) {                                                           \
  _Pragma("unroll")                                                           \
  for (int n = 0; n < 2; ++n) {                                               \
    bgv[n][0] = *(const bf16x8*)(GgB[n] + (size_t)(KT)*1024);                 \
    bgv[n][1] = *(const bf16x8*)(GgB[n] + (size_t)(KT)*1024 + 512);           \
    buv[n][0] = *(const bf16x8*)(UgB[n] + (size_t)(KT)*1024);                 \
    buv[n][1] = *(const bf16x8*)(UgB[n] + (size_t)(KT)*1024 + 512);           \
  } }
#define MMA1(ACC, MH, BV)                                                     \
  __builtin_amdgcn_s_setprio(1);                                              \
  _Pragma("unroll")                                                           \
  for (int m = 0; m < 4; ++m)                                                 \
  _Pragma("unroll")                                                           \
  for (int n = 0; n < 2; ++n) {                                               \
    ACC[(MH)*4+m][n] = __builtin_amdgcn_mfma_f32_16x16x32_bf16(av[m][0], BV[n][0], ACC[(MH)*4+m][n], 0,0,0); \
    ACC[(MH)*4+m][n] = __builtin_amdgcn_mfma_f32_16x16x32_bf16(av[m][1], BV[n][1], ACC[(MH)*4+m][n], 0,0,0); \
  }                                                                           \
  __builtin_amdgcn_s_setprio(0);

#define TILE1(B, U) {                                                         \
  LDBG1(U);                                 /* 8 coalesced global b128 */     \
  if ((U)+1 < NT1) { STA1((B)^1, 0, (U)+1); STA1((B)^1, 1, (U)+1); }          \
  FENCE();                                                                    \
  LDA1(B, 0);                               /* 8 ds_read_b128 (A only) */     \
  MMA1(accg, 0, bgv); MMA1(accu, 0, buv);                                     \
  LDA1(B, 1);                                                                 \
  MMA1(accu, 1, buv); MMA1(accg, 1, bgv);                                     \
  LGK0();                                                                     \
  if ((U)+1 < NT1) WVM0();                                                    \
  BARX(); FENCE();                                                            \
}

__global__ __launch_bounds__(512, 2) void gemm1_act_kernel(
    const unsigned short* __restrict__ xb,     // (T,H) bf16
    const unsigned short* __restrict__ w1g,    // packed (E*I/16,32,512)
    const unsigned short* __restrict__ w1u,    // packed
    const float* __restrict__ gub,             // (E,2I)
    const float* __restrict__ rw,              // (T,8)
    unsigned short* __restrict__ actW)         // (T,K2) bf16
{
  __shared__ unsigned short lds[2][16384];     // 64 KiB (A only)
  const int tid  = threadIdx.x;
  const int lane = tid & 63;
  const int wv   = tid >> 6;
  const int wm   = wv >> 2;                    // 0..1
  const int wn   = wv & 3;                     // 0..3

  // XCD-chunked swizzle (bijective)
  const int L  = blockIdx.x + 16 * blockIdx.y;
  const int xk = L & 7, xs = L >> 3;
  const int t0 = ((xk >> 1) * 4 + (xs & 3)) * 256;
  const int j0 = ((xk & 1) * 8 + (xs >> 2)) * 128;
  const int e  = blockIdx.z;

  const int arow = lane & 15;
  const int q    = lane >> 4;
  const int sw0  = ((q    ) ^ (arow & 7)) * 8;           // A read granule
  const int sw1  = ((q + 4) ^ (arow & 7)) * 8;
  const int sg   = ((tid & 7) ^ ((tid >> 3) & 7)) * 8;   // A stage source granule
  const int sl   = (tid & 7) * 8;                        // A stage LDS granule
  const int rA   = tid >> 3;                             // 0..63

  const unsigned short* Ag = xb + (size_t)t0 * H_;
  const int lofsB = arow * 32 + q * 8;
  const unsigned short* GgB[2];
  const unsigned short* UgB[2];
#pragma unroll
  for (int n = 0; n < 2; ++n) {
    const size_t jb = (size_t)(e * 128 + (j0 >> 4) + wn * 2 + n);
    GgB[n] = w1g + jb * 16384 + lofsB;
    UgB[n] = w1u + jb * 16384 + lofsB;
  }

  const f32x4 zero = {0.f, 0.f, 0.f, 0.f};
  f32x4 accg[8][2], accu[8][2];
#pragma unroll
  for (int m = 0; m < 8; ++m)
#pragma unroll
    for (int n = 0; n < 2; ++n) { accg[m][n] = zero; accu[m][n] = zero; }
  bf16x8 av[4][2], bgv[2][2], buv[2][2];

  // prologue: stage A(0) into buf0; drain; barrier.
  STA1(0, 0, 0); STA1(0, 1, 0);
  WVM0(); BARX(); FENCE();

#pragma unroll 1
  for (int t = 0; t < NT1; t += 2) {
    TILE1(0, t);
    TILE1(1, t+1);
  }

  // epilogue: C/D layout col=lane&15, row=(lane>>4)*4+reg
  const float* gbE = gub + (size_t)e * D2_;
#pragma unroll
  for (int n = 0; n < 2; ++n) {
    const int j = j0 + wn*32 + n*16 + arow;
    const float2 bgu = *(const float2*)&gbE[2*j];
#pragma unroll
    for (int mf = 0; mf < 8; ++mf) {
#pragma unroll
      for (int ri = 0; ri < 4; ++ri) {
        const int t = t0 + wm*128 + mf*16 + q*4 + ri;
        float g = accg[mf][n][ri] + bgu.x;
        float u = accu[mf][n][ri] + bgu.y;
        g = fminf(g, 7.0f);
        u = fminf(fmaxf(u, -7.0f), 7.0f);
        const float s   = 1.0f / (1.0f + __expf(-1.702f * g));
        const float val = (u + 1.0f) * (g * s) * rw[t * 8 + e];
        actW[(size_t)t * K2_ + e * I_ + j] = f2bf(val);
      }
    }
  }
}

// ============================================================================
// GEMM2: 256x256 tile, split-K=4, BK=64. A (actW) staged in LDS; B (w2t,
// packed) streamed global->registers. Same single-barrier ledger.
// ============================================================================

#define NT2 64

#define STA2(B, HF, KT) {                                                     \
  _Pragma("unroll")                                                           \
  for (int ld = 0; ld < 2; ++ld) {                                            \
    const int r = rA + (HF)*64 + ld*128;                                      \
    gll16(Ag + (size_t)r * K2_ + (KT)*64 + sg, &lds[B][r*64 + sl]);           \
  } }
#define LDA2(B, MH) {                                                         \
  _Pragma("unroll")                                                           \
  for (int m = 0; m < 4; ++m) {                                               \
    const int ro = (wm*128 + (MH)*64 + m*16 + arow) * 64;                     \
    av[m][0] = *(const bf16x8*)&lds[B][ro + sw0];                             \
    av[m][1] = *(const bf16x8*)&lds[B][ro + sw1];                             \
  } }
#define LDBG2(KT) {                                                           \
  _Pragma("unroll")                                                           \
  for (int n = 0; n < 2; ++n) {                                               \
    bv0[n][0] = *(const bf16x8*)(BgB[n]   + (size_t)(KT)*1024);               \
    bv0[n][1] = *(const bf16x8*)(BgB[n]   + (size_t)(KT)*1024 + 512);         \
    bv1[n][0] = *(const bf16x8*)(BgB[n+2] + (size_t)(KT)*1024);               \
    bv1[n][1] = *(const bf16x8*)(BgB[n+2] + (size_t)(KT)*1024 + 512);         \
  } }
#define MMA2(MH, NH, BV)                                                      \
  __builtin_amdgcn_s_setprio(1);                                              \
  _Pragma("unroll")                                                           \
  for (int m = 0; m < 4; ++m)                                                 \
  _Pragma("unroll")                                                           \
  for (int n = 0; n < 2; ++n) {                                               \
    acc[(MH)*4+m][(NH)*2+n] = __builtin_amdgcn_mfma_f32_16x16x32_bf16(av[m][0], BV[n][0], acc[(MH)*4+m][(NH)*2+n], 0,0,0); \
    acc[(MH)*4+m][(NH)*2+n] = __builtin_amdgcn_mfma_f32_16x16x32_bf16(av[m][1], BV[n][1], acc[(MH)*4+m][(NH)*2+n], 0,0,0); \
  }                                                                           \
  __builtin_amdgcn_s_setprio(0);

#define TILE2(B, U) {                                                         \
  LDBG2(U);                                                                   \
  if ((U)+1 < NT2) { STA2((B)^1, 0, (U)+1); STA2((B)^1, 1, (U)+1); }          \
  FENCE();                                                                    \
  LDA2(B, 0);                                                                 \
  MMA2(0, 0, bv0); MMA2(0, 1, bv1);                                           \
  LDA2(B, 1);                                                                 \
  MMA2(1, 0, bv0); MMA2(1, 1, bv1);                                           \
  LGK0();                                                                     \
  if ((U)+1 < NT2) WVM0();                                                    \
  BARX(); FENCE();                                                            \
}

__global__ __launch_bounds__(512, 2) void gemm2_kernel(
    const unsigned short* __restrict__ actW,   // (T,K2) bf16 row-major
    const unsigned short* __restrict__ w2t,    // packed (H/16,512,512)
    float* __restrict__ part)                  // (4,T,H) fp32
{
  __shared__ unsigned short lds[2][16384];     // 64 KiB (A only)
  const int tid  = threadIdx.x;
  const int lane = tid & 63;
  const int wv   = tid >> 6;
  const int wm   = wv >> 2;
  const int wn   = wv & 3;

  // XCD-chunked swizzle (bijective)
  const int L  = blockIdx.x + 16 * (blockIdx.y + 4 * blockIdx.z);
  const int xk = L & 7, xs = L >> 3;
  const int t0 = ((xk & 1) * 8 + (xs & 7)) * 256;
  const int h0 = (xs >> 3) * 256;
  const int cz = xk >> 1;
  const int c0 = cz * 4096;

  const int arow = lane & 15;
  const int q    = lane >> 4;
  const int sw0  = ((q    ) ^ (arow & 7)) * 8;
  const int sw1  = ((q + 4) ^ (arow & 7)) * 8;
  const int sg   = ((tid & 7) ^ ((tid >> 3) & 7)) * 8;
  const int sl   = (tid & 7) * 8;
  const int rA   = tid >> 3;

  const unsigned short* Ag = actW + (size_t)t0 * K2_ + c0;
  const int lofsB = arow * 32 + q * 8;
  const unsigned short* BgB[4];
#pragma unroll
  for (int nn = 0; nn < 4; ++nn)
    BgB[nn] = w2t + ((size_t)((h0 >> 4) + wn * 4 + nn) * 512 + (c0 >> 5)) * 512 + lofsB;

  const f32x4 zero = {0.f, 0.f, 0.f, 0.f};
  f32x4 acc[8][4];
#pragma unroll
  for (int m = 0; m < 8; ++m)
#pragma unroll
    for (int n = 0; n < 4; ++n) acc[m][n] = zero;
  bf16x8 av[4][2], bv0[2][2], bv1[2][2];

  // prologue: stage A(0) into buf0; drain; barrier.
  STA2(0, 0, 0); STA2(0, 1, 0);
  WVM0(); BARX(); FENCE();

#pragma unroll 1
  for (int t = 0; t < NT2; t += 2) {
    TILE2(0, t);
    TILE2(1, t+1);
  }

  float* P = part + (size_t)cz * ((size_t)T_ * H_);
#pragma unroll
  for (int mf = 0; mf < 8; ++mf)
#pragma unroll
    for (int nf = 0; nf < 4; ++nf)
#pragma unroll
      for (int ri = 0; ri < 4; ++ri) {
        const int t = t0 + wm*128 + mf*16 + q*4 + ri;
        const int h = h0 + wn*64 + nf*16 + arow;
        P[(size_t)t * H_ + h] = acc[mf][nf][ri];
      }
}

// ---- kernel 6: reduce partials + routed down-bias --------------------------
__global__ void reduce_kernel(const float* __restrict__ part,
                              const float* __restrict__ rw,
                              const float* __restrict__ dpb,
                              float* __restrict__ out) {
  const int idx = blockIdx.x * 256 + threadIdx.x;   // over T*H/4
  const int t  = idx >> 8;                          // H/4 = 256
  const int hq = idx & 255;
  const float4* p = (const float4*)part;
  float4 v = p[idx];
  float4 a;
  a = p[idx + 1048576]; v.x += a.x; v.y += a.y; v.z += a.z; v.w += a.w;
  a = p[idx + 2097152]; v.x += a.x; v.y += a.y; v.z += a.z; v.w += a.w;
  a = p[idx + 3145728]; v.x += a.x; v.y += a.y; v.z += a.z; v.w += a.w;
  const float4 w0 = *(const float4*)(rw + t*8);
  const float4 w1 = *(const float4*)(rw + t*8 + 4);
  const float wgt[8] = {w0.x, w0.y, w0.z, w0.w, w1.x, w1.y, w1.z, w1.w};
  const float4* db = (const float4*)dpb;
#pragma unroll
  for (int e2 = 0; e2 < 8; ++e2) {
    float4 b = db[e2*256 + hq];
    v.x += wgt[e2]*b.x; v.y += wgt[e2]*b.y; v.z += wgt[e2]*b.z; v.w += wgt[e2]*b.w;
  }
  ((float4*)out)[idx] = v;
}

extern "C" void kernel_launch(void* const* d_in, const int* in_sizes, int n_in,
                              void* d_out, int out_size, void* d_ws, size_t ws_size,
                              hipStream_t stream) {
  const float* hs  = (const float*)d_in[0];
  const float* rw  = (const float*)d_in[1];
  const float* gup = (const float*)d_in[2];
  const float* gub = (const float*)d_in[3];
  const float* dp  = (const float*)d_in[4];
  const float* dpb = (const float*)d_in[5];
  float* out = (float*)d_out;

  char* ws = (char*)d_ws;
  unsigned short* xb   = (unsigned short*)(ws);                 //   8 MiB @ 0
  unsigned short* w1g  = (unsigned short*)(ws + 8388608);       //  32 MiB
  unsigned short* w1u  = (unsigned short*)(ws + 41943040);      //  32 MiB
  float*          part = (float*)(ws + 8388608);                //  64 MiB (reuses w1g/w1u after gemm1)
  unsigned short* w2t  = (unsigned short*)(ws + 75497472);      //  32 MiB
  unsigned short* actW = (unsigned short*)(ws + 109051904);     // 128 MiB

  hipLaunchKernelGGL(cast_x_kernel, dim3((T_ * H_) / 2048), dim3(256), 0, stream, hs, xb);
  hipLaunchKernelGGL(transp_w1_kernel, dim3(H_/64, D2_/64, E_), dim3(256), 0, stream, gup, w1g, w1u);
  hipLaunchKernelGGL(transp_w2_kernel, dim3(K2_/64, H_/64), dim3(256), 0, stream, dp, w2t);
  hipLaunchKernelGGL(gemm1_act_kernel, dim3(T_/256, I_/128, E_), dim3(512), 0, stream,
                     xb, w1g, w1u, gub, rw, actW);
  hipLaunchKernelGGL(gemm2_kernel, dim3(T_/256, H_/256, 4), dim3(512), 0, stream,
                     actW, w2t, part);
  hipLaunchKernelGGL(reduce_kernel, dim3((T_ * H_ / 4) / 256), dim3(256), 0, stream,
                     part, rw, dpb, out);
}

// Round 11
// 437.892 us; speedup vs baseline: 1.2461x; 1.2461x over previous
//
#include <hip/hip_runtime.h>
#include <cstdint>

#define E_  8
#define H_  1024
#define I_  2048
#define T_  4096
#define D2_ 4096      // 2*I
#define K2_ 16384     // E*I

typedef __bf16 bf16x8 __attribute__((ext_vector_type(8)));
typedef float  f32x4  __attribute__((ext_vector_type(4)));

__device__ __forceinline__ unsigned short f2bf(float f) {
  unsigned int u = __float_as_uint(f);
  u += 0x7FFFu + ((u >> 16) & 1u);           // round-to-nearest-even
  return (unsigned short)(u >> 16);
}

// async global->LDS, 16B per lane. LDS dest must be wave-uniform base + lane*16.
__device__ __forceinline__ void gll16(const void* g, void* l) {
  __builtin_amdgcn_global_load_lds(
      (const __attribute__((address_space(1))) unsigned int*)(uintptr_t)g,
      (__attribute__((address_space(3))) unsigned int*)(uintptr_t)l,
      16, 0, 0);
}

#define BARX()  __builtin_amdgcn_s_barrier()
#define FENCE() __builtin_amdgcn_sched_barrier(0)
#define WLG()   { asm volatile("s_waitcnt lgkmcnt(0)" ::: "memory"); __builtin_amdgcn_sched_barrier(0); }
#define LGK0()  asm volatile("s_waitcnt lgkmcnt(0)" ::: "memory")
#define WVM4()  asm volatile("s_waitcnt vmcnt(4)" ::: "memory")
#define WVM0()  asm volatile("s_waitcnt vmcnt(0)" ::: "memory")

// ---------------- kernel 1: cast hidden_states fp32 -> bf16 ----------------
__global__ void cast_x_kernel(const float* __restrict__ x,
                              unsigned short* __restrict__ xb) {
  const int idx = (blockIdx.x * 256 + threadIdx.x) * 8;
  float4 a = *(const float4*)(x + idx);
  float4 b = *(const float4*)(x + idx + 4);
  unsigned short o[8];
  o[0]=f2bf(a.x); o[1]=f2bf(a.y); o[2]=f2bf(a.z); o[3]=f2bf(a.w);
  o[4]=f2bf(b.x); o[5]=f2bf(b.y); o[6]=f2bf(b.z); o[7]=f2bf(b.w);
  *(uint4*)(xb + idx) = *(const uint4*)o;
}

// ---- kernel 2: gate_up_proj (E,H,2I) fp32 -> W1g/W1u (E,I,H) bf16 ----------
__global__ void transp_w1_kernel(const float* __restrict__ gup,
                                 unsigned short* __restrict__ w1g,
                                 unsigned short* __restrict__ w1u) {
  __shared__ float tile[64][65];
  const int h0 = blockIdx.x * 64;
  const int d0 = blockIdx.y * 64;
  const int e  = blockIdx.z;
  const int tid = threadIdx.x;
  const int r  = tid >> 4;
  const int c4 = (tid & 15) * 4;
  const float* src = gup + ((size_t)e * H_ + h0) * D2_ + d0;
#pragma unroll
  for (int c = 0; c < 4; ++c) {
    const int row = r + 16 * c;
    float4 v = *(const float4*)(src + (size_t)row * D2_ + c4);
    tile[row][c4+0] = v.x; tile[row][c4+1] = v.y;
    tile[row][c4+2] = v.z; tile[row][c4+3] = v.w;
  }
  __syncthreads();
  const int hl = tid & 63;
  const int jg = tid >> 6;
  const size_t jbase = (size_t)e * I_ + (d0 >> 1);
#pragma unroll
  for (int jj = 0; jj < 8; ++jj) {
    const int jl = jg * 8 + jj;
    w1g[(jbase + jl) * H_ + h0 + hl] = f2bf(tile[hl][2*jl]);
    w1u[(jbase + jl) * H_ + h0 + hl] = f2bf(tile[hl][2*jl+1]);
  }
}

// ---- kernel 3: down_proj (E,I,H) fp32 -> W2T (H, E*I) bf16 -----------------
__global__ void transp_w2_kernel(const float* __restrict__ dp,
                                 unsigned short* __restrict__ w2t) {
  __shared__ float tile[64][65];
  const int k0 = blockIdx.x * 64;
  const int h0 = blockIdx.y * 64;
  const int tid = threadIdx.x;
  const int r  = tid >> 4;
  const int c4 = (tid & 15) * 4;
#pragma unroll
  for (int c = 0; c < 4; ++c) {
    const int row = r + 16 * c;
    float4 v = *(const float4*)(dp + (size_t)(k0 + row) * H_ + h0 + c4);
    tile[row][c4+0] = v.x; tile[row][c4+1] = v.y;
    tile[row][c4+2] = v.z; tile[row][c4+3] = v.w;
  }
  __syncthreads();
  const int kl = tid & 63;
  const int hg = tid >> 6;
#pragma unroll
  for (int hh = 0; hh < 16; ++hh) {
    const int hl = hg * 16 + hh;
    w2t[(size_t)(h0 + hl) * K2_ + k0 + kl] = f2bf(tile[kl][hl]);
  }
}

// ============================================================================
// GEMM1 — R4 build, measured 273 us (MfmaUtil 45%): 256x128 tile, 2 half-tiles
// per K-tile, 2 barriers, WVM4 at tile end. A/Bg/Bu all gll16-staged.
// LDS (per buf, shorts): A[256*64] @0, Bg[128*64] @16384, Bu[128*64] @24576.
// Swizzle: physical granule = logical granule ^ (row&7)   (granule = 8 shorts)
// ============================================================================

#define STA1(B, HF, KT) {                                                    \
  _Pragma("unroll")                                                           \
  for (int ld = 0; ld < 2; ++ld) {                                            \
    const int r = rA + (HF)*64 + ld*128;                                      \
    gll16(Ag + (size_t)r * H_ + (KT)*64 + sg, &lds[B][r*64 + sl]);            \
  } }
#define STG1(B, KT) {                                                         \
  _Pragma("unroll")                                                           \
  for (int ld = 0; ld < 2; ++ld) {                                            \
    const int r = rA + ld*64;                                                 \
    gll16(Gg + (size_t)r * H_ + (KT)*64 + sg, &lds[B][16384 + r*64 + sl]);    \
  } }
#define STU1(B, KT) {                                                         \
  _Pragma("unroll")                                                           \
  for (int ld = 0; ld < 2; ++ld) {                                            \
    const int r = rA + ld*64;                                                 \
    gll16(Ug + (size_t)r * H_ + (KT)*64 + sg, &lds[B][24576 + r*64 + sl]);    \
  } }
#define LDA1(B, MH) {                                                         \
  _Pragma("unroll")                                                           \
  for (int m = 0; m < 4; ++m) {                                               \
    const int ro = (wm*128 + (MH)*64 + m*16 + arow) * 64;                     \
    av[m][0] = *(const bf16x8*)&lds[B][ro + sw0];                             \
    av[m][1] = *(const bf16x8*)&lds[B][ro + sw1];                             \
  } }
#define LDB1(B, DST, BASE) {                                                  \
  _Pragma("unroll")                                                           \
  for (int n = 0; n < 2; ++n) {                                               \
    const int ro = (BASE) + (wn*32 + n*16 + arow) * 64;                       \
    DST[n][0] = *(const bf16x8*)&lds[B][ro + sw0];                            \
    DST[n][1] = *(const bf16x8*)&lds[B][ro + sw1];                            \
  } }
#define MMA1(ACC, MH, BV)                                                     \
  __builtin_amdgcn_s_setprio(1);                                              \
  _Pragma("unroll")                                                           \
  for (int m = 0; m < 4; ++m)                                                 \
  _Pragma("unroll")                                                           \
  for (int n = 0; n < 2; ++n) {                                               \
    ACC[(MH)*4+m][n] = __builtin_amdgcn_mfma_f32_16x16x32_bf16(av[m][0], BV[n][0], ACC[(MH)*4+m][n], 0,0,0); \
    ACC[(MH)*4+m][n] = __builtin_amdgcn_mfma_f32_16x16x32_bf16(av[m][1], BV[n][1], ACC[(MH)*4+m][n], 0,0,0); \
  }                                                                           \
  __builtin_amdgcn_s_setprio(0);

#define NT1 16
#define TILE1(B, U) {                                                         \
  /* half-A: all frag reads for MH0 + both B operands, stage t+1 -> buf^1 */  \
  LDA1(B, 0); LDB1(B, bgv, 16384); LDB1(B, buv, 24576);                       \
  if ((U)+1 < NT1) { STA1((B)^1, 1, (U)+1); STG1((B)^1, (U)+1); }             \
  WLG();                                                                      \
  MMA1(accg, 0, bgv); MMA1(accu, 0, buv);                                     \
  BARX();                                                                     \
  /* half-B: MH1 frags, stage t+2 -> buf (regions disjoint from MH1 reads) */ \
  LDA1(B, 1);                                                                 \
  if ((U)+2 < NT1) { STA1(B, 0, (U)+2); STU1(B, (U)+2); }                     \
  WLG();                                                                      \
  MMA1(accu, 1, buv); MMA1(accg, 1, bgv);                                     \
  if ((U)+2 < NT1) { WVM4(); } else { WVM0(); }                               \
  BARX();                                                                     \
}

__global__ __launch_bounds__(512, 2) void gemm1_act_kernel(
    const unsigned short* __restrict__ xb,     // (T,H) bf16
    const unsigned short* __restrict__ w1g,    // (E,I,H) bf16
    const unsigned short* __restrict__ w1u,    // (E,I,H) bf16
    const float* __restrict__ gub,             // (E,2I)
    const float* __restrict__ rw,              // (T,8)
    unsigned short* __restrict__ actW)         // (T,K2) bf16
{
  __shared__ unsigned short lds[2][32768];     // 128 KiB
  const int tid  = threadIdx.x;
  const int lane = tid & 63;
  const int wv   = tid >> 6;
  const int wm   = wv >> 2;                    // 0..1
  const int wn   = wv & 3;                     // 0..3

  // XCD-chunked swizzle: L mod 8 = XCD; XCD k gets t-tiles [(k>>1)*4, +4) x
  // j-tiles [(k&1)*8, +8).  Bijective.
  const int L  = blockIdx.x + 16 * blockIdx.y;
  const int xk = L & 7, xs = L >> 3;
  const int t0 = ((xk >> 1) * 4 + (xs & 3)) * 256;
  const int j0 = ((xk & 1) * 8 + (xs >> 2)) * 128;
  const int e  = blockIdx.z;

  const int arow = lane & 15;
  const int q    = lane >> 4;
  const int sw0  = ((q    ) ^ (arow & 7)) * 8;           // shorts
  const int sw1  = ((q + 4) ^ (arow & 7)) * 8;
  const int sg   = ((tid & 7) ^ ((tid >> 3) & 7)) * 8;   // stage: swizzled global granule
  const int sl   = (tid & 7) * 8;                        // stage: linear LDS granule
  const int rA   = tid >> 3;                             // 0..63

  const unsigned short* Ag = xb  + (size_t)t0 * H_;
  const unsigned short* Gg = w1g + ((size_t)e * I_ + j0) * H_;
  const unsigned short* Ug = w1u + ((size_t)e * I_ + j0) * H_;

  const f32x4 zero = {0.f, 0.f, 0.f, 0.f};
  f32x4 accg[8][2], accu[8][2];
#pragma unroll
  for (int m = 0; m < 8; ++m)
#pragma unroll
    for (int n = 0; n < 2; ++n) { accg[m][n] = zero; accu[m][n] = zero; }
  bf16x8 av[4][2], bgv[2][2], buv[2][2];

  // prologue (R4 ledger): after WVM4, buf0 fully staged, 4 ops flying
  STA1(0, 0, 0); STU1(0, 0); STA1(0, 1, 0); STG1(0, 0);
  STA1(1, 0, 1); STU1(1, 1);
  WVM4(); BARX();

#pragma unroll 1
  for (int t = 0; t < NT1; t += 2) {
    TILE1(0, t);
    TILE1(1, t+1);
  }

  // epilogue: C/D layout col=lane&15, row=(lane>>4)*4+reg
  const float* gbE = gub + (size_t)e * D2_;
#pragma unroll
  for (int n = 0; n < 2; ++n) {
    const int j = j0 + wn*32 + n*16 + arow;
    const float2 bgu = *(const float2*)&gbE[2*j];
#pragma unroll
    for (int mf = 0; mf < 8; ++mf) {
#pragma unroll
      for (int ri = 0; ri < 4; ++ri) {
        const int t = t0 + wm*128 + mf*16 + q*4 + ri;
        float g = accg[mf][n][ri] + bgu.x;
        float u = accu[mf][n][ri] + bgu.y;
        g = fminf(g, 7.0f);
        u = fminf(fmaxf(u, -7.0f), 7.0f);
        const float s   = 1.0f / (1.0f + __expf(-1.702f * g));
        const float val = (u + 1.0f) * (g * s) * rw[t * 8 + e];
        actW[(size_t)t * K2_ + e * I_ + j] = f2bf(val);
      }
    }
  }
}

// ============================================================================
// GEMM2 — R5 build, measured ~107 us: 256x256 tile, split-K=4, BK=64,
// ONE barrier + one lgkm drain + one vmcnt drain per K-tile, all-LDS staging,
// XCD-chunked swizzle. LDS (per buf, shorts): A[256*64] @0, B[256*64] @16384.
// ============================================================================

#define STA2(B, HF, KT) {                                                    \
  _Pragma("unroll")                                                           \
  for (int ld = 0; ld < 2; ++ld) {                                            \
    const int r = rA + (HF)*64 + ld*128;                                      \
    gll16(Ag + (size_t)r * K2_ + (KT)*64 + sg, &lds[B][r*64 + sl]);           \
  } }
#define STB2(B, NH, KT) {                                                    \
  _Pragma("unroll")                                                           \
  for (int ld = 0; ld < 2; ++ld) {                                            \
    const int lr = rA + ld*64;                                                \
    const int r  = (lr & 31) + (NH)*32 + ((lr >> 5) << 6);                    \
    gll16(Bgp + (size_t)r * K2_ + (KT)*64 + sg, &lds[B][16384 + r*64 + sl]);  \
  } }
#define LDA2(B, MH) {                                                         \
  _Pragma("unroll")                                                           \
  for (int m = 0; m < 4; ++m) {                                               \
    const int ro = (wm*128 + (MH)*64 + m*16 + arow) * 64;                     \
    av[m][0] = *(const bf16x8*)&lds[B][ro + sw0];                             \
    av[m][1] = *(const bf16x8*)&lds[B][ro + sw1];                             \
  } }
#define LDB2(B, DST, NH) {                                                   \
  _Pragma("unroll")                                                           \
  for (int n = 0; n < 2; ++n) {                                               \
    const int ro = 16384 + (wn*64 + (NH)*32 + n*16 + arow) * 64;              \
    DST[n][0] = *(const bf16x8*)&lds[B][ro + sw0];                            \
    DST[n][1] = *(const bf16x8*)&lds[B][ro + sw1];                            \
  } }
#define MMA2(MH, NH, BV)                                                      \
  __builtin_amdgcn_s_setprio(1);                                              \
  _Pragma("unroll")                                                           \
  for (int m = 0; m < 4; ++m)                                                 \
  _Pragma("unroll")                                                           \
  for (int n = 0; n < 2; ++n) {                                               \
    acc[(MH)*4+m][(NH)*2+n] = __builtin_amdgcn_mfma_f32_16x16x32_bf16(av[m][0], BV[n][0], acc[(MH)*4+m][(NH)*2+n], 0,0,0); \
    acc[(MH)*4+m][(NH)*2+n] = __builtin_amdgcn_mfma_f32_16x16x32_bf16(av[m][1], BV[n][1], acc[(MH)*4+m][(NH)*2+n], 0,0,0); \
  }                                                                           \
  __builtin_amdgcn_s_setprio(0);

#define NT2 64
#define TILE2(B, U) {                                                         \
  if ((U)+1 < NT2) { STA2((B)^1, 0, (U)+1); STA2((B)^1, 1, (U)+1);            \
                     STB2((B)^1, 0, (U)+1); STB2((B)^1, 1, (U)+1); }          \
  FENCE();                                                                    \
  LDA2(B, 0); LDB2(B, bv0, 0); LDB2(B, bv1, 1);                               \
  MMA2(0, 0, bv0); MMA2(0, 1, bv1);                                           \
  LDA2(B, 1);                                                                 \
  MMA2(1, 0, bv0); MMA2(1, 1, bv1);                                           \
  LGK0();                                                                     \
  if ((U)+1 < NT2) WVM0();                                                    \
  BARX();                                                                     \
  FENCE();                                                                    \
}

__global__ __launch_bounds__(512, 2) void gemm2_kernel(
    const unsigned short* __restrict__ actW,   // (T,K2) bf16
    const unsigned short* __restrict__ w2t,    // (H,K2) bf16
    float* __restrict__ part)                  // (4,T,H) fp32
{
  __shared__ unsigned short lds[2][32768];     // 128 KiB
  const int tid  = threadIdx.x;
  const int lane = tid & 63;
  const int wv   = tid >> 6;
  const int wm   = wv >> 2;
  const int wn   = wv & 3;

  // XCD-chunked swizzle: XCD k = L mod 8 owns t-tiles [(k&1)*8, +8), all 4
  // h-tiles, c-slice (k>>1).  Bijective.
  const int L  = blockIdx.x + 16 * (blockIdx.y + 4 * blockIdx.z);
  const int xk = L & 7, xs = L >> 3;
  const int t0 = ((xk & 1) * 8 + (xs & 7)) * 256;
  const int h0 = (xs >> 3) * 256;
  const int cz = xk >> 1;
  const int c0 = cz * 4096;

  const int arow = lane & 15;
  const int q    = lane >> 4;
  const int sw0  = ((q    ) ^ (arow & 7)) * 8;
  const int sw1  = ((q + 4) ^ (arow & 7)) * 8;
  const int sg   = ((tid & 7) ^ ((tid >> 3) & 7)) * 8;
  const int sl   = (tid & 7) * 8;
  const int rA   = tid >> 3;

  const unsigned short* Ag  = actW + (size_t)t0 * K2_ + c0;
  const unsigned short* Bgp = w2t  + (size_t)h0 * K2_ + c0;

  const f32x4 zero = {0.f, 0.f, 0.f, 0.f};
  f32x4 acc[8][4];
#pragma unroll
  for (int m = 0; m < 8; ++m)
#pragma unroll
    for (int n = 0; n < 4; ++n) acc[m][n] = zero;
  bf16x8 av[4][2], bv0[2][2], bv1[2][2];

  // prologue: stage tile 0 fully into buf0; drain; barrier.
  STA2(0, 0, 0); STA2(0, 1, 0); STB2(0, 0, 0); STB2(0, 1, 0);
  WVM0(); BARX(); FENCE();

#pragma unroll 1
  for (int t = 0; t < NT2; t += 2) {
    TILE2(0, t);
    TILE2(1, t+1);
  }

  float* P = part + (size_t)cz * ((size_t)T_ * H_);
#pragma unroll
  for (int mf = 0; mf < 8; ++mf)
#pragma unroll
    for (int nf = 0; nf < 4; ++nf)
#pragma unroll
      for (int ri = 0; ri < 4; ++ri) {
        const int t = t0 + wm*128 + mf*16 + q*4 + ri;
        const int h = h0 + wn*64 + nf*16 + arow;
        P[(size_t)t * H_ + h] = acc[mf][nf][ri];
      }
}

// ---- kernel 6: reduce partials + routed down-bias --------------------------
__global__ void reduce_kernel(const float* __restrict__ part,
                              const float* __restrict__ rw,
                              const float* __restrict__ dpb,
                              float* __restrict__ out) {
  const int idx = blockIdx.x * 256 + threadIdx.x;   // over T*H/4
  const int t  = idx >> 8;                          // H/4 = 256
  const int hq = idx & 255;
  const float4* p = (const float4*)part;
  float4 v = p[idx];
  float4 a;
  a = p[idx + 1048576]; v.x += a.x; v.y += a.y; v.z += a.z; v.w += a.w;
  a = p[idx + 2097152]; v.x += a.x; v.y += a.y; v.z += a.z; v.w += a.w;
  a = p[idx + 3145728]; v.x += a.x; v.y += a.y; v.z += a.z; v.w += a.w;
  const float4 w0 = *(const float4*)(rw + t*8);
  const float4 w1 = *(const float4*)(rw + t*8 + 4);
  const float wgt[8] = {w0.x, w0.y, w0.z, w0.w, w1.x, w1.y, w1.z, w1.w};
  const float4* db = (const float4*)dpb;
#pragma unroll
  for (int e2 = 0; e2 < 8; ++e2) {
    float4 b = db[e2*256 + hq];
    v.x += wgt[e2]*b.x; v.y += wgt[e2]*b.y; v.z += wgt[e2]*b.z; v.w += wgt[e2]*b.w;
  }
  ((float4*)out)[idx] = v;
}

extern "C" void kernel_launch(void* const* d_in, const int* in_sizes, int n_in,
                              void* d_out, int out_size, void* d_ws, size_t ws_size,
                              hipStream_t stream) {
  const float* hs  = (const float*)d_in[0];
  const float* rw  = (const float*)d_in[1];
  const float* gup = (const float*)d_in[2];
  const float* gub = (const float*)d_in[3];
  const float* dp  = (const float*)d_in[4];
  const float* dpb = (const float*)d_in[5];
  float* out = (float*)d_out;

  char* ws = (char*)d_ws;
  unsigned short* xb   = (unsigned short*)(ws);                 //   8 MiB @ 0
  unsigned short* w1g  = (unsigned short*)(ws + 8388608);       //  32 MiB
  unsigned short* w1u  = (unsigned short*)(ws + 41943040);      //  32 MiB
  float*          part = (float*)(ws + 8388608);                //  64 MiB (reuses w1g/w1u after gemm1)
  unsigned short* w2t  = (unsigned short*)(ws + 75497472);      //  32 MiB
  unsigned short* actW = (unsigned short*)(ws + 109051904);     // 128 MiB

  hipLaunchKernelGGL(cast_x_kernel, dim3((T_ * H_) / 2048), dim3(256), 0, stream, hs, xb);
  hipLaunchKernelGGL(transp_w1_kernel, dim3(H_/64, D2_/64, E_), dim3(256), 0, stream, gup, w1g, w1u);
  hipLaunchKernelGGL(transp_w2_kernel, dim3(K2_/64, H_/64), dim3(256), 0, stream, dp, w2t);
  hipLaunchKernelGGL(gemm1_act_kernel, dim3(T_/256, I_/128, E_), dim3(512), 0, stream,
                     xb, w1g, w1u, gub, rw, actW);
  hipLaunchKernelGGL(gemm2_kernel, dim3(T_/256, H_/256, 4), dim3(512), 0, stream,
                     actW, w2t, part);
  hipLaunchKernelGGL(reduce_kernel, dim3((T_ * H_ / 4) / 256), dim3(256), 0, stream,
                     part, rw, dpb, out);
}